// Round 16
// baseline (6273.240 us; speedup 1.0000x reference)
//
#include <hip/hip_runtime.h>
#include <stdint.h>

// ---------------------------------------------------------------------------
// ODE-RNN encoder, f32 I/O, bf16 MFMA internals.
// R16 = R14 ode core restored verbatim (3.11 ms; L2/latency floor for this
// structure — M=64 needs >=144 regs vs the measured 128 budget, and
// global-state variants need ~+192MB vs the ws wall found in R15: 273MB
// faulted, <=76MB passes) + gru_step reworked:
//  - register-double-buffered staging (issue kk+1's loads during kk's MFMAs)
//  - lgkm-only barriers (R14's __syncthreads drained vmcnt(0) every kk,
//    serializing the weight stream).
// Workspace footprint: 72.5 MB (same as R14).
// ---------------------------------------------------------------------------

typedef __bf16 bf16x8 __attribute__((ext_vector_type(8)));
typedef float floatx4 __attribute__((ext_vector_type(4)));

#define BP 40  // gru padded B row (ushorts)

static __device__ __forceinline__ float bf2f(unsigned short u) {
  union { unsigned int u32; float f; } c;
  c.u32 = ((unsigned int)u) << 16;
  return c.f;
}
static __device__ __forceinline__ unsigned short f2bf(float f) {
  union { __bf16 h; unsigned short u; } c;
  c.h = (__bf16)f;  // RNE
  return c.u;
}

// LDS-only barrier: does NOT drain vmcnt, so global prefetches stay in flight.
static __device__ __forceinline__ void barrier_lds() {
  __asm__ volatile("s_waitcnt lgkmcnt(0)\n\ts_barrier" ::: "memory");
}

// ---------------------------------------------------------------------------
// tile_weight: W (K=512 x N=512, f32 row-major) -> bf16 tiled
// [kk(16)][nt(32)][qd(4)][ml(16)][8]; element (kk,nt,qd,ml,j) = W[kk*32+qd*8+j][nt*16+ml]
// ---------------------------------------------------------------------------
__global__ void tile_weight(const float* __restrict__ src, unsigned short* __restrict__ dst) {
  int t = blockIdx.x * 256 + threadIdx.x;  // 0..32767
  int ml = t & 15, qd = (t >> 4) & 3;
  int nt = (t >> 6) & 31, kk = t >> 11;
  int n = nt * 16 + ml;
  int k0 = kk * 32 + qd * 8;
  unsigned short o[8] __attribute__((aligned(16)));
#pragma unroll
  for (int j = 0; j < 8; ++j) o[j] = f2bf(src[(size_t)(k0 + j) * 512 + n]);
  *(uint4*)(dst + (size_t)t * 8) = *(const uint4*)o;
}

// ---------------------------------------------------------------------------
// transpose + f32->bf16 (GRU weights, [n][k] flat layout)
// ---------------------------------------------------------------------------
__global__ void transpose_f2b(const float* __restrict__ src, unsigned short* __restrict__ dst,
                              int R, int C) {
  __shared__ float t[32][33];
  int c0 = blockIdx.x * 32, r0 = blockIdx.y * 32;
  int tx = threadIdx.x, ty = threadIdx.y;  // 32 x 8
#pragma unroll
  for (int i = 0; i < 32; i += 8) t[ty + i][tx] = src[(size_t)(r0 + ty + i) * C + c0 + tx];
  __syncthreads();
#pragma unroll
  for (int i = 0; i < 32; i += 8) dst[(size_t)(c0 + ty + i) * R + r0 + tx] = f2bf(t[tx][ty + i]);
}

// ---------------------------------------------------------------------------
// obs embed: y = leaky(LN(xs @ W + b)) (f32 in, bf16 out), one wave per row
// ---------------------------------------------------------------------------
__global__ __launch_bounds__(256) void obs_embed(
    const float* __restrict__ xs, const float* __restrict__ W,
    const float* __restrict__ bias, const float* __restrict__ gam,
    const float* __restrict__ bet, unsigned short* __restrict__ Y) {
  __shared__ float Wl[4096];
  const int tid = threadIdx.x, lane = tid & 63, wv = tid >> 6;
#pragma unroll
  for (int i = 0; i < 16; ++i) Wl[i * 256 + tid] = W[i * 256 + tid];
  __syncthreads();
  size_t row = (size_t)blockIdx.x * 4 + wv;
  float xf[8];
  {
    const float* xp = xs + row * 8;
#pragma unroll
    for (int k = 0; k < 8; ++k) xf[k] = xp[k];
  }
  int n0 = lane * 8;
  float a[8];
#pragma unroll
  for (int j = 0; j < 8; ++j) a[j] = bias[n0 + j];
#pragma unroll
  for (int k = 0; k < 8; ++k)
#pragma unroll
    for (int j = 0; j < 8; ++j) a[j] += xf[k] * Wl[k * 512 + n0 + j];
  float s1 = 0.f, s2 = 0.f;
#pragma unroll
  for (int j = 0; j < 8; ++j) { s1 += a[j]; s2 += a[j] * a[j]; }
#pragma unroll
  for (int off = 1; off < 64; off <<= 1) { s1 += __shfl_xor(s1, off); s2 += __shfl_xor(s2, off); }
  float mean = s1 * (1.f / 512.f);
  float rstd = rsqrtf(s2 * (1.f / 512.f) - mean * mean + 1e-5f);
  unsigned short o[8] __attribute__((aligned(16)));
#pragma unroll
  for (int j = 0; j < 8; ++j) {
    float v = (a[j] - mean) * rstd * gam[n0 + j] + bet[n0 + j];
    v = v > 0.f ? v : 0.01f * v;
    o[j] = f2bf(v);
  }
  *(uint4*)(Y + row * 512 + n0) = *(const uint4*)o;
}

// ---------------------------------------------------------------------------
// ODE megakernel (R14, unchanged). A (32x512) tiled in LDS; 8 waves, each
// M=32 x N=64; B global->VGPR dbuf; K-loop barrier-free.
// ---------------------------------------------------------------------------

// element (row, n) address in tiled A (ushort index), row < 32
static __device__ __forceinline__ int a_addr(int row, int n) {
  return (((row >> 4) * 16 + (n >> 5)) * 4 + ((n >> 3) & 3)) * 128 + (row & 15) * 8 + (n & 7);
}

static __device__ __forceinline__ void bload(const unsigned short* __restrict__ Wt, int kk,
                                             int wv, int lane, bf16x8 (&b)[4]) {
#pragma unroll
  for (int j = 0; j < 4; ++j)
    b[j] = *(const bf16x8*)(Wt + ((size_t)kk * 32 + 4 * wv + j) * 512 + (size_t)lane * 8);
}

// bb must hold Wt slabs {0,1} on entry; holds Wnext slabs {0,1} on exit.
static __device__ __forceinline__ void gemmS(const unsigned short* __restrict__ Wt,
                                             const unsigned short* __restrict__ Wnext,
                                             const unsigned short* As, int wv, int lane,
                                             bf16x8 (&bb)[2][4], floatx4 (&acc)[2][4]) {
#pragma unroll
  for (int mi = 0; mi < 2; ++mi)
#pragma unroll
    for (int j = 0; j < 4; ++j) acc[mi][j] = 0.f;
#pragma unroll 2
  for (int kk = 0; kk < 16; ++kk) {  // unroll 2 (dbuf parity), NOT full (R5-R8 lesson)
    bf16x8 a[2];
#pragma unroll
    for (int mi = 0; mi < 2; ++mi) a[mi] = *(const bf16x8*)&As[(mi * 16 + kk) * 512 + lane * 8];
#pragma unroll
    for (int mi = 0; mi < 2; ++mi)
#pragma unroll
      for (int j = 0; j < 4; ++j)
        acc[mi][j] =
            __builtin_amdgcn_mfma_f32_16x16x32_bf16(a[mi], bb[kk & 1][j], acc[mi][j], 0, 0, 0);
    // refill the just-consumed slot: kk+2 of this weight, or next weight's 0/1
    if (kk < 14) bload(Wt, kk + 2, wv, lane, bb[kk & 1]);
    else bload(Wnext, kk - 14, wv, lane, bb[kk & 1]);
  }
}

// LN + leaky epilogue; 8-wave reduction; writes bf16 result into tiled As.
static __device__ __forceinline__ void ln_epi(floatx4 (&acc)[2][4], unsigned short* As,
                                              const unsigned short* Ps, int pb, int pg, int pbe,
                                              bool addt, float tval, int wv, int lane, int tid,
                                              float2* red, float* stat) {
  const int ml = lane & 15, qd = lane >> 4;
#pragma unroll
  for (int j = 0; j < 4; ++j) {
    int n = (4 * wv + j) * 16 + ml;
    float bias = bf2f(Ps[pb * 512 + n]);
    if (addt) bias += tval * bf2f(Ps[512 + n]);
#pragma unroll
    for (int mi = 0; mi < 2; ++mi)
#pragma unroll
      for (int r = 0; r < 4; ++r) acc[mi][j][r] += bias;
  }
#pragma unroll
  for (int mi = 0; mi < 2; ++mi)
#pragma unroll
    for (int r = 0; r < 4; ++r) {
      float s1 = 0.f, s2 = 0.f;
#pragma unroll
      for (int j = 0; j < 4; ++j) { float x = acc[mi][j][r]; s1 += x; s2 += x * x; }
#pragma unroll
      for (int off = 1; off < 16; off <<= 1) { s1 += __shfl_xor(s1, off); s2 += __shfl_xor(s2, off); }
      if (ml == 0) red[(mi * 16 + 4 * qd + r) * 8 + wv] = make_float2(s1, s2);
    }
  barrier_lds();  // red visible; all waves past their As a-frag reads
  if (tid < 32) {
    float S1 = 0.f, S2 = 0.f;
#pragma unroll
    for (int w = 0; w < 8; ++w) { float2 v = red[tid * 8 + w]; S1 += v.x; S2 += v.y; }
    float mean = S1 * (1.f / 512.f);
    float var = S2 * (1.f / 512.f) - mean * mean;
    stat[tid * 2] = mean;
    stat[tid * 2 + 1] = rsqrtf(var + 1e-5f);
  }
  barrier_lds();
#pragma unroll
  for (int mi = 0; mi < 2; ++mi)
#pragma unroll
    for (int r = 0; r < 4; ++r) {
      int row = mi * 16 + 4 * qd + r;
      float mean = stat[row * 2], rstd = stat[row * 2 + 1];
#pragma unroll
      for (int j = 0; j < 4; ++j) {
        int n = (4 * wv + j) * 16 + ml;
        float x = (acc[mi][j][r] - mean) * rstd * bf2f(Ps[pg * 512 + n]) + bf2f(Ps[pbe * 512 + n]);
        x = x > 0.f ? x : 0.01f * x;
        As[a_addr(row, n)] = f2bf(x);
      }
    }
  barrier_lds();  // As writes visible
}

// RK4 stage: k = acc + bout; h fp32 regs, ksum packed bf16 pairs; writes y
// into As; on the final stage also writes h_ode to Yb.
static __device__ __forceinline__ void stage_epi(floatx4 (&acc)[2][4], float (&h)[2][4][4],
                                                 unsigned int (&ks)[2][4][2], unsigned short* As,
                                                 unsigned short* Yb, size_t m0,
                                                 const unsigned short* Ps, int stg, bool last,
                                                 int wv, int lane) {
  const int ml = lane & 15, qd = lane >> 4;
  barrier_lds();  // K-loop has no barriers: ensure all waves done reading As
#pragma unroll
  for (int mi = 0; mi < 2; ++mi)
#pragma unroll
    for (int j = 0; j < 4; ++j) {
      int n = (4 * wv + j) * 16 + ml;
      float bias = bf2f(Ps[7 * 512 + n]);
#pragma unroll
      for (int rp = 0; rp < 2; ++rp) {
        float kv0 = acc[mi][j][2 * rp] + bias;
        float kv1 = acc[mi][j][2 * rp + 1] + bias;
        unsigned int pk = ks[mi][j][rp];
        float s0 = bf2f((unsigned short)(pk & 0xffffu));
        float s1 = bf2f((unsigned short)(pk >> 16));
        float h0 = h[mi][j][2 * rp], h1 = h[mi][j][2 * rp + 1];
        float y0, y1;
        if (stg == 0)      { s0 = kv0;        s1 = kv1;        y0 = h0 + 0.125f * kv0; y1 = h1 + 0.125f * kv1; }
        else if (stg == 1) { s0 += 2.f * kv0; s1 += 2.f * kv1; y0 = h0 + 0.125f * kv0; y1 = h1 + 0.125f * kv1; }
        else if (stg == 2) { s0 += 2.f * kv0; s1 += 2.f * kv1; y0 = h0 + 0.25f * kv0;  y1 = h1 + 0.25f * kv1; }
        else {
          h0 += (1.f / 24.f) * (s0 + kv0);  // dt/6, dt=0.25
          h1 += (1.f / 24.f) * (s1 + kv1);
          h[mi][j][2 * rp] = h0; h[mi][j][2 * rp + 1] = h1;
          y0 = h0; y1 = h1;
        }
        ks[mi][j][rp] = (unsigned int)f2bf(s0) | ((unsigned int)f2bf(s1) << 16);
        int row = mi * 16 + 4 * qd + 2 * rp;
        As[a_addr(row, n)] = f2bf(y0);
        As[a_addr(row + 1, n)] = f2bf(y1);
        if (last && stg == 3) {
          Yb[(m0 + row) * 512 + n] = f2bf(y0);
          Yb[(m0 + row + 1) * 512 + n] = f2bf(y1);
        }
      }
    }
  barrier_lds();  // As writes visible
}

__global__ __launch_bounds__(512) void ode_mega(
    unsigned short* Yb, const unsigned short* __restrict__ W1t,
    const unsigned short* __restrict__ W2t, const unsigned short* __restrict__ Wot,
    const float* __restrict__ b1, const float* __restrict__ tr, const float* __restrict__ g1,
    const float* __restrict__ be1, const float* __restrict__ b2, const float* __restrict__ g2,
    const float* __restrict__ be2, const float* __restrict__ bo) {
  __shared__ __align__(16) unsigned short As[16384];  // 32KB tiled A (32 rows)
  __shared__ __align__(16) unsigned short Ps[4096];   // 8KB params
  __shared__ float2 red[256];                         // 2KB: 32 rows x 8 waves
  __shared__ float stat[64];                          // 256B -> ~42.3KB, 2 blocks/CU

  const int tid = threadIdx.x;
  const int lane = tid & 63;
  const int wv = tid >> 6;  // 0..7
  const int ml = lane & 15;
  const int qd = lane >> 4;
  const size_t m0 = (size_t)blockIdx.x * 32;

  // start weight prefetch immediately
  bf16x8 bb[2][4];
  bload(W1t, 0, wv, lane, bb[0]);
  bload(W1t, 1, wv, lane, bb[1]);

  {
    const float* srcs[8] = {b1, tr, g1, be1, b2, g2, be2, bo};
#pragma unroll
    for (int v = 0; v < 8; ++v) Ps[v * 512 + tid] = f2bf(srcs[v][tid]);
  }
  // stage As: thread owns row r = tid>>4, chunks c = i*16 + (tid&15)
  {
    int r = tid >> 4;  // 0..31
#pragma unroll
    for (int i = 0; i < 4; ++i) {
      int c = i * 16 + (tid & 15);
      uint4 v = *(const uint4*)(Yb + (m0 + r) * 512 + c * 8);
      int dst = (((r >> 4) * 16 + (c >> 2)) * 4 + (c & 3)) * 128 + (r & 15) * 8;
      *(uint4*)(As + dst) = v;
    }
  }
  barrier_lds();

  float h[2][4][4];          // fp32 ODE state, MFMA C-layout
  unsigned int ks[2][4][2];  // RK4 ksum, packed bf16 pairs
#pragma unroll
  for (int mi = 0; mi < 2; ++mi)
#pragma unroll
    for (int j = 0; j < 4; ++j) {
      ks[mi][j][0] = 0u; ks[mi][j][1] = 0u;
      int n = (4 * wv + j) * 16 + ml;
#pragma unroll
      for (int r = 0; r < 4; ++r) h[mi][j][r] = bf2f(As[a_addr(mi * 16 + 4 * qd + r, n)]);
    }

  for (int e = 0; e < 16; ++e) {  // 4 RK4 steps x 4 stages
    int stg = e & 3;
    float tval = 0.25f * (float)(e >> 2) + ((stg == 3) ? 0.25f : (stg ? 0.125f : 0.f));
    floatx4 acc[2][4];
    gemmS(W1t, W2t, As, wv, lane, bb, acc);
    ln_epi(acc, As, Ps, 0, 2, 3, true, tval, wv, lane, tid, red, stat);
    gemmS(W2t, Wot, As, wv, lane, bb, acc);
    ln_epi(acc, As, Ps, 4, 5, 6, false, 0.f, wv, lane, tid, red, stat);
    gemmS(Wot, W1t, As, wv, lane, bb, acc);  // preloads next eval's W1
    stage_epi(acc, h, ks, As, Yb, m0, Ps, stg, e == 15, wv, lane);
  }
}

// ---------------------------------------------------------------------------
// GRU step: gi = y_t @ W_ih, gh = h_prev @ W_hh (6 gate groups), gates.
// grid (32, 8): 32 rows x 64 gate-cols per block, 4 waves.
// R16: register-double-buffered staging (issue kk+1 during kk's MFMAs) and
// lgkm-only barriers (no vmcnt(0) drain per kk).
// Chunk ownership (1792 chunks of 16B over 256 threads, 7 each):
//   slot0: tid<128 -> Yt chunk tid; tid>=128 -> hprev chunk tid-128
//   slots1..6: Bg chunk (c-1)*256 + tid   (g = idb>>8, rem = idb&255)
// ---------------------------------------------------------------------------
__global__ __launch_bounds__(256) void gru_step(
    const unsigned short* __restrict__ Yt, const float* __restrict__ hprev,
    float* __restrict__ hnew, const unsigned short* __restrict__ Wiht,
    const unsigned short* __restrict__ Whht, const float* __restrict__ bih,
    const float* __restrict__ bhh) {
  __shared__ __align__(16) unsigned short Ay[32 * BP];
  __shared__ __align__(16) unsigned short Ah[32 * BP];
  __shared__ __align__(16) unsigned short Bg[6 * 64 * BP];
  const int tid = threadIdx.x, lane = tid & 63, wv = tid >> 6;
  const int ml = lane & 15, qd = lane >> 4;
  const int m0 = blockIdx.x * 32;
  const int j0 = blockIdx.y * 64;

  floatx4 acc[2][6];
#pragma unroll
  for (int mi = 0; mi < 2; ++mi)
#pragma unroll
    for (int g = 0; g < 6; ++g) acc[mi][g] = 0.f;

  uint4 st0;          // Yt chunk (tid<128)
  float4 hf4a, hf4b;  // hprev chunk (tid>=128)
  uint4 stb[6];       // Bg chunks

  auto issue = [&](int kk) {
    if (tid < 128) {
      int r = tid >> 2, kc = tid & 3;
      st0 = *(const uint4*)(Yt + (size_t)(m0 + r) * 512 + kk * 32 + kc * 8);
    } else {
      int id = tid - 128;
      int r = id >> 2, kc = id & 3;
      const float* s = hprev + (size_t)(m0 + r) * 512 + kk * 32 + kc * 8;
      hf4a = *(const float4*)s;
      hf4b = *(const float4*)(s + 4);
    }
#pragma unroll
    for (int c = 0; c < 6; ++c) {
      int idb = c * 256 + tid;  // 0..1535
      int g = idb >> 8, rem = idb & 255;
      int r = rem >> 2, kc = rem & 3;
      const unsigned short* mat = (g < 3) ? Wiht : Whht;
      int gate = (g < 3) ? g : (g - 3);
      stb[c] = *(const uint4*)(mat + (size_t)(gate * 512 + j0 + r) * 512 + kk * 32 + kc * 8);
    }
  };
  auto commit = [&]() {
    if (tid < 128) {
      *(uint4*)(Ay + (tid >> 2) * BP + (tid & 3) * 8) = st0;
    } else {
      int id = tid - 128;
      unsigned short o[8] __attribute__((aligned(16)));
      o[0] = f2bf(hf4a.x); o[1] = f2bf(hf4a.y); o[2] = f2bf(hf4a.z); o[3] = f2bf(hf4a.w);
      o[4] = f2bf(hf4b.x); o[5] = f2bf(hf4b.y); o[6] = f2bf(hf4b.z); o[7] = f2bf(hf4b.w);
      *(uint4*)(Ah + (id >> 2) * BP + (id & 3) * 8) = *(const uint4*)o;
    }
#pragma unroll
    for (int c = 0; c < 6; ++c) {
      int idb = c * 256 + tid;
      int g = idb >> 8, rem = idb & 255;
      int r = rem >> 2, kc = rem & 3;
      *(uint4*)(Bg + g * (64 * BP) + r * BP + kc * 8) = stb[c];
    }
  };

  issue(0);
  for (int kk = 0; kk < 16; ++kk) {
    commit();
    barrier_lds();               // staging visible (ds_writes tracked by lgkm)
    if (kk < 15) issue(kk + 1);  // loads fly during the MFMA phase
    bf16x8 ay[2], ah[2];
#pragma unroll
    for (int mi = 0; mi < 2; ++mi) {
      ay[mi] = *(const bf16x8*)&Ay[(16 * mi + ml) * BP + qd * 8];
      ah[mi] = *(const bf16x8*)&Ah[(16 * mi + ml) * BP + qd * 8];
    }
#pragma unroll
    for (int g = 0; g < 6; ++g) {
      bf16x8 b = *(const bf16x8*)&Bg[g * (64 * BP) + (16 * wv + ml) * BP + qd * 8];
#pragma unroll
      for (int mi = 0; mi < 2; ++mi)
        acc[mi][g] = __builtin_amdgcn_mfma_f32_16x16x32_bf16((g < 3) ? ay[mi] : ah[mi], b,
                                                             acc[mi][g], 0, 0, 0);
    }
    barrier_lds();  // LDS reads done before next commit overwrites
  }
  int j = j0 + 16 * wv + ml;
  float bi_r = bih[j], bi_z = bih[512 + j], bi_n = bih[1024 + j];
  float bh_r = bhh[j], bh_z = bhh[512 + j], bh_n = bhh[1024 + j];
#pragma unroll
  for (int mi = 0; mi < 2; ++mi)
#pragma unroll
    for (int r = 0; r < 4; ++r) {
      size_t row = (size_t)(m0 + 16 * mi + 4 * qd + r);
      float rg = acc[mi][0][r] + bi_r + acc[mi][3][r] + bh_r;
      rg = 1.f / (1.f + __expf(-rg));
      float zg = acc[mi][1][r] + bi_z + acc[mi][4][r] + bh_z;
      zg = 1.f / (1.f + __expf(-zg));
      float ng = tanhf(acc[mi][2][r] + bi_n + rg * (acc[mi][5][r] + bh_n));
      float hp = hprev[row * 512 + j];
      hnew[row * 512 + j] = (1.f - zg) * ng + zg * hp;
    }
}

__global__ void zero_h(float* hf) {
  int i = blockIdx.x * 256 + threadIdx.x;
  hf[i] = 0.f;
}

// ---------------------------------------------------------------------------
extern "C" void kernel_launch(void* const* d_in, const int* in_sizes, int n_in,
                              void* d_out, int out_size, void* d_ws, size_t ws_size,
                              hipStream_t stream) {
  (void)in_sizes; (void)n_in; (void)out_size; (void)ws_size;
  const float* xs    = (const float*)d_in[0];
  const float* obsW  = (const float*)d_in[1];
  const float* obsb  = (const float*)d_in[2];
  const float* obsg  = (const float*)d_in[3];
  const float* obsbe = (const float*)d_in[4];
  const float* W1    = (const float*)d_in[5];
  const float* b1    = (const float*)d_in[6];
  const float* g1    = (const float*)d_in[7];
  const float* be1   = (const float*)d_in[8];
  const float* W2    = (const float*)d_in[9];
  const float* b2    = (const float*)d_in[10];
  const float* g2    = (const float*)d_in[11];
  const float* be2   = (const float*)d_in[12];
  const float* Wo    = (const float*)d_in[13];
  const float* bo    = (const float*)d_in[14];
  const float* Wih   = (const float*)d_in[15];
  const float* bih   = (const float*)d_in[16];
  const float* Whh   = (const float*)d_in[17];
  const float* bhh   = (const float*)d_in[18];

  char* p = (char*)d_ws;
  auto take = [&](size_t bytes) { char* q = p; p += (bytes + 255) & ~(size_t)255; return q; };
  unsigned short* W1t  = (unsigned short*)take((size_t)512 * 512 * 2);
  unsigned short* W2t  = (unsigned short*)take((size_t)512 * 512 * 2);
  unsigned short* Wot  = (unsigned short*)take((size_t)512 * 512 * 2);
  unsigned short* Wiht = (unsigned short*)take((size_t)1536 * 512 * 2);
  unsigned short* Whht = (unsigned short*)take((size_t)1536 * 512 * 2);
  float* hf0 = (float*)take((size_t)1024 * 512 * 4);
  float* hf1 = (float*)take((size_t)1024 * 512 * 4);
  unsigned short* Yb = (unsigned short*)take((size_t)65536 * 512 * 2);

  dim3 tb(32, 8);
  tile_weight<<<128, 256, 0, stream>>>(W1, W1t);  // first 512 of 513 rows
  tile_weight<<<128, 256, 0, stream>>>(W2, W2t);
  tile_weight<<<128, 256, 0, stream>>>(Wo, Wot);
  transpose_f2b<<<dim3(48, 16), tb, 0, stream>>>(Wih, Wiht, 512, 1536);
  transpose_f2b<<<dim3(48, 16), tb, 0, stream>>>(Whh, Whht, 512, 1536);

  obs_embed<<<16384, 256, 0, stream>>>(xs, obsW, obsb, obsg, obsbe, Yb);

  // tr = W1 row 512 (time row), folded into layer-1 bias per eval.
  ode_mega<<<2048, 512, 0, stream>>>(Yb, W1t, W2t, Wot, b1, W1 + 512 * 512, g1, be1, b2, g2,
                                     be2, bo);

  zero_h<<<2048, 256, 0, stream>>>(hf0);
  float* hf[2] = {hf0, hf1};
  for (int t = 0; t < 64; ++t) {
    int s = t & 1, d = s ^ 1;
    float* hn = (t == 63) ? (float*)d_out : hf[d];
    gru_step<<<dim3(32, 8), 256, 0, stream>>>(Yb + (size_t)t * 1024 * 512, hf[s], hn, Wiht, Whht,
                                              bih, bhh);
  }
}

// Round 17
// 4078.883 us; speedup vs baseline: 1.5380x; 1.5380x over previous
//
#include <hip/hip_runtime.h>
#include <stdint.h>

// ---------------------------------------------------------------------------
// ODE-RNN encoder, f32 I/O, bf16 MFMA internals.  (R17 = R14 verbatim — best
// verified state. Session-measured constraints that close the option space:
//  * VGPR budget law: regs/wave = 131072/(2*threads) regardless of LDS or
//    attributes (R4-R10) -> M=64/wave (needs >=144) unreachable; M=32 w/
//    8 waves/block + 2 blocks/CU = 16 waves/CU is the TLP optimum (R14).
//  * Compiler sinks plain-load prefetches (R11) and the global_load_lds DMA
//    round-trip adds unhidden LDS latency (R12/R13) -> simple 2-slab
//    global->VGPR dbuf is the best B path.
//  * Workspace wall between 76MB (ok) and 273MB (faults) -> no materialized
//    Gi / global RK4 state (R15).
//  * GRU step is launch+L2-latency bound at ~13us/step; both pipelining
//    reworks regressed (R15 crash, R16 3x slower) -> keep simple form.)
// ---------------------------------------------------------------------------

typedef __bf16 bf16x8 __attribute__((ext_vector_type(8)));
typedef float floatx4 __attribute__((ext_vector_type(4)));

#define BP 40  // gru padded B row (ushorts)

static __device__ __forceinline__ float bf2f(unsigned short u) {
  union { unsigned int u32; float f; } c;
  c.u32 = ((unsigned int)u) << 16;
  return c.f;
}
static __device__ __forceinline__ unsigned short f2bf(float f) {
  union { __bf16 h; unsigned short u; } c;
  c.h = (__bf16)f;  // RNE
  return c.u;
}

// LDS-only barrier: does NOT drain vmcnt, so global prefetches stay in flight.
static __device__ __forceinline__ void barrier_lds() {
  __asm__ volatile("s_waitcnt lgkmcnt(0)\n\ts_barrier" ::: "memory");
}

// ---------------------------------------------------------------------------
// tile_weight: W (K=512 x N=512, f32 row-major) -> bf16 tiled
// [kk(16)][nt(32)][qd(4)][ml(16)][8]; element (kk,nt,qd,ml,j) = W[kk*32+qd*8+j][nt*16+ml]
// ---------------------------------------------------------------------------
__global__ void tile_weight(const float* __restrict__ src, unsigned short* __restrict__ dst) {
  int t = blockIdx.x * 256 + threadIdx.x;  // 0..32767
  int ml = t & 15, qd = (t >> 4) & 3;
  int nt = (t >> 6) & 31, kk = t >> 11;
  int n = nt * 16 + ml;
  int k0 = kk * 32 + qd * 8;
  unsigned short o[8] __attribute__((aligned(16)));
#pragma unroll
  for (int j = 0; j < 8; ++j) o[j] = f2bf(src[(size_t)(k0 + j) * 512 + n]);
  *(uint4*)(dst + (size_t)t * 8) = *(const uint4*)o;
}

// ---------------------------------------------------------------------------
// transpose + f32->bf16 (GRU weights, [n][k] flat layout)
// ---------------------------------------------------------------------------
__global__ void transpose_f2b(const float* __restrict__ src, unsigned short* __restrict__ dst,
                              int R, int C) {
  __shared__ float t[32][33];
  int c0 = blockIdx.x * 32, r0 = blockIdx.y * 32;
  int tx = threadIdx.x, ty = threadIdx.y;  // 32 x 8
#pragma unroll
  for (int i = 0; i < 32; i += 8) t[ty + i][tx] = src[(size_t)(r0 + ty + i) * C + c0 + tx];
  __syncthreads();
#pragma unroll
  for (int i = 0; i < 32; i += 8) dst[(size_t)(c0 + ty + i) * R + r0 + tx] = f2bf(t[tx][ty + i]);
}

// ---------------------------------------------------------------------------
// obs embed: y = leaky(LN(xs @ W + b)) (f32 in, bf16 out), one wave per row
// ---------------------------------------------------------------------------
__global__ __launch_bounds__(256) void obs_embed(
    const float* __restrict__ xs, const float* __restrict__ W,
    const float* __restrict__ bias, const float* __restrict__ gam,
    const float* __restrict__ bet, unsigned short* __restrict__ Y) {
  __shared__ float Wl[4096];
  const int tid = threadIdx.x, lane = tid & 63, wv = tid >> 6;
#pragma unroll
  for (int i = 0; i < 16; ++i) Wl[i * 256 + tid] = W[i * 256 + tid];
  __syncthreads();
  size_t row = (size_t)blockIdx.x * 4 + wv;
  float xf[8];
  {
    const float* xp = xs + row * 8;
#pragma unroll
    for (int k = 0; k < 8; ++k) xf[k] = xp[k];
  }
  int n0 = lane * 8;
  float a[8];
#pragma unroll
  for (int j = 0; j < 8; ++j) a[j] = bias[n0 + j];
#pragma unroll
  for (int k = 0; k < 8; ++k)
#pragma unroll
    for (int j = 0; j < 8; ++j) a[j] += xf[k] * Wl[k * 512 + n0 + j];
  float s1 = 0.f, s2 = 0.f;
#pragma unroll
  for (int j = 0; j < 8; ++j) { s1 += a[j]; s2 += a[j] * a[j]; }
#pragma unroll
  for (int off = 1; off < 64; off <<= 1) { s1 += __shfl_xor(s1, off); s2 += __shfl_xor(s2, off); }
  float mean = s1 * (1.f / 512.f);
  float rstd = rsqrtf(s2 * (1.f / 512.f) - mean * mean + 1e-5f);
  unsigned short o[8] __attribute__((aligned(16)));
#pragma unroll
  for (int j = 0; j < 8; ++j) {
    float v = (a[j] - mean) * rstd * gam[n0 + j] + bet[n0 + j];
    v = v > 0.f ? v : 0.01f * v;
    o[j] = f2bf(v);
  }
  *(uint4*)(Y + row * 512 + n0) = *(const uint4*)o;
}

// ---------------------------------------------------------------------------
// ODE megakernel. A (32x512) resident in tiled LDS [mt][kk][qd][ml][8];
// 8 waves, each owning M=32 (2 mi) x N=64 (nt = 4*wv .. 4*wv+3).
// B fragments stream global->VGPR dbuf; K-loop barrier-free.
// ---------------------------------------------------------------------------

// element (row, n) address in tiled A (ushort index), row < 32
static __device__ __forceinline__ int a_addr(int row, int n) {
  return (((row >> 4) * 16 + (n >> 5)) * 4 + ((n >> 3) & 3)) * 128 + (row & 15) * 8 + (n & 7);
}

static __device__ __forceinline__ void bload(const unsigned short* __restrict__ Wt, int kk,
                                             int wv, int lane, bf16x8 (&b)[4]) {
#pragma unroll
  for (int j = 0; j < 4; ++j)
    b[j] = *(const bf16x8*)(Wt + ((size_t)kk * 32 + 4 * wv + j) * 512 + (size_t)lane * 8);
}

// bb must hold Wt slabs {0,1} on entry; holds Wnext slabs {0,1} on exit.
static __device__ __forceinline__ void gemmS(const unsigned short* __restrict__ Wt,
                                             const unsigned short* __restrict__ Wnext,
                                             const unsigned short* As, int wv, int lane,
                                             bf16x8 (&bb)[2][4], floatx4 (&acc)[2][4]) {
#pragma unroll
  for (int mi = 0; mi < 2; ++mi)
#pragma unroll
    for (int j = 0; j < 4; ++j) acc[mi][j] = 0.f;
#pragma unroll 2
  for (int kk = 0; kk < 16; ++kk) {  // unroll 2 (dbuf parity), NOT full (R5-R8 lesson)
    bf16x8 a[2];
#pragma unroll
    for (int mi = 0; mi < 2; ++mi) a[mi] = *(const bf16x8*)&As[(mi * 16 + kk) * 512 + lane * 8];
#pragma unroll
    for (int mi = 0; mi < 2; ++mi)
#pragma unroll
      for (int j = 0; j < 4; ++j)
        acc[mi][j] =
            __builtin_amdgcn_mfma_f32_16x16x32_bf16(a[mi], bb[kk & 1][j], acc[mi][j], 0, 0, 0);
    // refill the just-consumed slot: kk+2 of this weight, or next weight's 0/1
    if (kk < 14) bload(Wt, kk + 2, wv, lane, bb[kk & 1]);
    else bload(Wnext, kk - 14, wv, lane, bb[kk & 1]);
  }
}

// LN + leaky epilogue; 8-wave reduction; writes bf16 result into tiled As.
static __device__ __forceinline__ void ln_epi(floatx4 (&acc)[2][4], unsigned short* As,
                                              const unsigned short* Ps, int pb, int pg, int pbe,
                                              bool addt, float tval, int wv, int lane, int tid,
                                              float2* red, float* stat) {
  const int ml = lane & 15, qd = lane >> 4;
#pragma unroll
  for (int j = 0; j < 4; ++j) {
    int n = (4 * wv + j) * 16 + ml;
    float bias = bf2f(Ps[pb * 512 + n]);
    if (addt) bias += tval * bf2f(Ps[512 + n]);
#pragma unroll
    for (int mi = 0; mi < 2; ++mi)
#pragma unroll
      for (int r = 0; r < 4; ++r) acc[mi][j][r] += bias;
  }
#pragma unroll
  for (int mi = 0; mi < 2; ++mi)
#pragma unroll
    for (int r = 0; r < 4; ++r) {
      float s1 = 0.f, s2 = 0.f;
#pragma unroll
      for (int j = 0; j < 4; ++j) { float x = acc[mi][j][r]; s1 += x; s2 += x * x; }
#pragma unroll
      for (int off = 1; off < 16; off <<= 1) { s1 += __shfl_xor(s1, off); s2 += __shfl_xor(s2, off); }
      if (ml == 0) red[(mi * 16 + 4 * qd + r) * 8 + wv] = make_float2(s1, s2);
    }
  barrier_lds();  // red visible; all waves past their As a-frag reads
  if (tid < 32) {
    float S1 = 0.f, S2 = 0.f;
#pragma unroll
    for (int w = 0; w < 8; ++w) { float2 v = red[tid * 8 + w]; S1 += v.x; S2 += v.y; }
    float mean = S1 * (1.f / 512.f);
    float var = S2 * (1.f / 512.f) - mean * mean;
    stat[tid * 2] = mean;
    stat[tid * 2 + 1] = rsqrtf(var + 1e-5f);
  }
  barrier_lds();
#pragma unroll
  for (int mi = 0; mi < 2; ++mi)
#pragma unroll
    for (int r = 0; r < 4; ++r) {
      int row = mi * 16 + 4 * qd + r;
      float mean = stat[row * 2], rstd = stat[row * 2 + 1];
#pragma unroll
      for (int j = 0; j < 4; ++j) {
        int n = (4 * wv + j) * 16 + ml;
        float x = (acc[mi][j][r] - mean) * rstd * bf2f(Ps[pg * 512 + n]) + bf2f(Ps[pbe * 512 + n]);
        x = x > 0.f ? x : 0.01f * x;
        As[a_addr(row, n)] = f2bf(x);
      }
    }
  barrier_lds();  // As writes visible
}

// RK4 stage: k = acc + bout; h fp32 regs, ksum packed bf16 pairs; writes y
// into As; on the final stage also writes h_ode to Yb.
static __device__ __forceinline__ void stage_epi(floatx4 (&acc)[2][4], float (&h)[2][4][4],
                                                 unsigned int (&ks)[2][4][2], unsigned short* As,
                                                 unsigned short* Yb, size_t m0,
                                                 const unsigned short* Ps, int stg, bool last,
                                                 int wv, int lane) {
  const int ml = lane & 15, qd = lane >> 4;
  barrier_lds();  // K-loop has no barriers: ensure all waves done reading As
#pragma unroll
  for (int mi = 0; mi < 2; ++mi)
#pragma unroll
    for (int j = 0; j < 4; ++j) {
      int n = (4 * wv + j) * 16 + ml;
      float bias = bf2f(Ps[7 * 512 + n]);
#pragma unroll
      for (int rp = 0; rp < 2; ++rp) {
        float kv0 = acc[mi][j][2 * rp] + bias;
        float kv1 = acc[mi][j][2 * rp + 1] + bias;
        unsigned int pk = ks[mi][j][rp];
        float s0 = bf2f((unsigned short)(pk & 0xffffu));
        float s1 = bf2f((unsigned short)(pk >> 16));
        float h0 = h[mi][j][2 * rp], h1 = h[mi][j][2 * rp + 1];
        float y0, y1;
        if (stg == 0)      { s0 = kv0;        s1 = kv1;        y0 = h0 + 0.125f * kv0; y1 = h1 + 0.125f * kv1; }
        else if (stg == 1) { s0 += 2.f * kv0; s1 += 2.f * kv1; y0 = h0 + 0.125f * kv0; y1 = h1 + 0.125f * kv1; }
        else if (stg == 2) { s0 += 2.f * kv0; s1 += 2.f * kv1; y0 = h0 + 0.25f * kv0;  y1 = h1 + 0.25f * kv1; }
        else {
          h0 += (1.f / 24.f) * (s0 + kv0);  // dt/6, dt=0.25
          h1 += (1.f / 24.f) * (s1 + kv1);
          h[mi][j][2 * rp] = h0; h[mi][j][2 * rp + 1] = h1;
          y0 = h0; y1 = h1;
        }
        ks[mi][j][rp] = (unsigned int)f2bf(s0) | ((unsigned int)f2bf(s1) << 16);
        int row = mi * 16 + 4 * qd + 2 * rp;
        As[a_addr(row, n)] = f2bf(y0);
        As[a_addr(row + 1, n)] = f2bf(y1);
        if (last && stg == 3) {
          Yb[(m0 + row) * 512 + n] = f2bf(y0);
          Yb[(m0 + row + 1) * 512 + n] = f2bf(y1);
        }
      }
    }
  barrier_lds();  // As writes visible
}

__global__ __launch_bounds__(512) void ode_mega(
    unsigned short* Yb, const unsigned short* __restrict__ W1t,
    const unsigned short* __restrict__ W2t, const unsigned short* __restrict__ Wot,
    const float* __restrict__ b1, const float* __restrict__ tr, const float* __restrict__ g1,
    const float* __restrict__ be1, const float* __restrict__ b2, const float* __restrict__ g2,
    const float* __restrict__ be2, const float* __restrict__ bo) {
  __shared__ __align__(16) unsigned short As[16384];  // 32KB tiled A (32 rows)
  __shared__ __align__(16) unsigned short Ps[4096];   // 8KB params
  __shared__ float2 red[256];                         // 2KB: 32 rows x 8 waves
  __shared__ float stat[64];                          // 256B -> ~42.3KB, 2 blocks/CU

  const int tid = threadIdx.x;
  const int lane = tid & 63;
  const int wv = tid >> 6;  // 0..7
  const int ml = lane & 15;
  const int qd = lane >> 4;
  const size_t m0 = (size_t)blockIdx.x * 32;

  // start weight prefetch immediately
  bf16x8 bb[2][4];
  bload(W1t, 0, wv, lane, bb[0]);
  bload(W1t, 1, wv, lane, bb[1]);

  {
    const float* srcs[8] = {b1, tr, g1, be1, b2, g2, be2, bo};
#pragma unroll
    for (int v = 0; v < 8; ++v) Ps[v * 512 + tid] = f2bf(srcs[v][tid]);
  }
  // stage As: thread owns row r = tid>>4, chunks c = i*16 + (tid&15)
  {
    int r = tid >> 4;  // 0..31
#pragma unroll
    for (int i = 0; i < 4; ++i) {
      int c = i * 16 + (tid & 15);
      uint4 v = *(const uint4*)(Yb + (m0 + r) * 512 + c * 8);
      int dst = (((r >> 4) * 16 + (c >> 2)) * 4 + (c & 3)) * 128 + (r & 15) * 8;
      *(uint4*)(As + dst) = v;
    }
  }
  barrier_lds();

  float h[2][4][4];          // fp32 ODE state, MFMA C-layout
  unsigned int ks[2][4][2];  // RK4 ksum, packed bf16 pairs
#pragma unroll
  for (int mi = 0; mi < 2; ++mi)
#pragma unroll
    for (int j = 0; j < 4; ++j) {
      ks[mi][j][0] = 0u; ks[mi][j][1] = 0u;
      int n = (4 * wv + j) * 16 + ml;
#pragma unroll
      for (int r = 0; r < 4; ++r) h[mi][j][r] = bf2f(As[a_addr(mi * 16 + 4 * qd + r, n)]);
    }

  for (int e = 0; e < 16; ++e) {  // 4 RK4 steps x 4 stages
    int stg = e & 3;
    float tval = 0.25f * (float)(e >> 2) + ((stg == 3) ? 0.25f : (stg ? 0.125f : 0.f));
    floatx4 acc[2][4];
    gemmS(W1t, W2t, As, wv, lane, bb, acc);
    ln_epi(acc, As, Ps, 0, 2, 3, true, tval, wv, lane, tid, red, stat);
    gemmS(W2t, Wot, As, wv, lane, bb, acc);
    ln_epi(acc, As, Ps, 4, 5, 6, false, 0.f, wv, lane, tid, red, stat);
    gemmS(Wot, W1t, As, wv, lane, bb, acc);  // preloads next eval's W1
    stage_epi(acc, h, ks, As, Yb, m0, Ps, stg, e == 15, wv, lane);
  }
}

// ---------------------------------------------------------------------------
// GRU step: gi = y_t @ W_ih, gh = h_prev @ W_hh, gates.
// grid (32, 8): 32 rows x 64 gate-cols per block, 4 waves.
// ---------------------------------------------------------------------------
__global__ __launch_bounds__(256) void gru_step(
    const unsigned short* __restrict__ Yt, const float* __restrict__ hprev,
    float* __restrict__ hnew, const unsigned short* __restrict__ Wiht,
    const unsigned short* __restrict__ Whht, const float* __restrict__ bih,
    const float* __restrict__ bhh) {
  __shared__ __align__(16) unsigned short Ay[32 * BP];
  __shared__ __align__(16) unsigned short Ah[32 * BP];
  __shared__ __align__(16) unsigned short Bg[6 * 64 * BP];
  const int tid = threadIdx.x, lane = tid & 63, wv = tid >> 6;
  const int ml = lane & 15, qd = lane >> 4;
  const int m0 = blockIdx.x * 32;
  const int j0 = blockIdx.y * 64;

  floatx4 acc[2][6];
#pragma unroll
  for (int mi = 0; mi < 2; ++mi)
#pragma unroll
    for (int g = 0; g < 6; ++g) acc[mi][g] = 0.f;

  for (int kk = 0; kk < 16; ++kk) {
    __syncthreads();
#pragma unroll
    for (int c = 0; c < 7; ++c) {
      int id = c * 256 + tid;
      if (id < 128) {
        int r = id >> 2, kc = id & 3;
        *(uint4*)(Ay + r * BP + kc * 8) =
            *(const uint4*)(Yt + (size_t)(m0 + r) * 512 + kk * 32 + kc * 8);
      } else if (id < 256) {
        int id2 = id - 128;
        int r = id2 >> 2, kc = id2 & 3;
        const float* s = hprev + (size_t)(m0 + r) * 512 + kk * 32 + kc * 8;
        unsigned short o[8] __attribute__((aligned(16)));
#pragma unroll
        for (int j = 0; j < 8; ++j) o[j] = f2bf(s[j]);
        *(uint4*)(Ah + r * BP + kc * 8) = *(const uint4*)o;
      } else {
        int id2 = id - 256;
        int g = id2 >> 8;
        int rem = id2 & 255;
        int r = rem >> 2, kc = rem & 3;
        const unsigned short* mat = (g < 3) ? Wiht : Whht;
        int gate = (g < 3) ? g : (g - 3);
        *(uint4*)(Bg + g * (64 * BP) + r * BP + kc * 8) =
            *(const uint4*)(mat + (size_t)(gate * 512 + j0 + r) * 512 + kk * 32 + kc * 8);
      }
    }
    __syncthreads();
    bf16x8 ay[2], ah[2];
#pragma unroll
    for (int mi = 0; mi < 2; ++mi) {
      ay[mi] = *(const bf16x8*)&Ay[(16 * mi + ml) * BP + qd * 8];
      ah[mi] = *(const bf16x8*)&Ah[(16 * mi + ml) * BP + qd * 8];
    }
#pragma unroll
    for (int g = 0; g < 6; ++g) {
      bf16x8 b = *(const bf16x8*)&Bg[g * (64 * BP) + (16 * wv + ml) * BP + qd * 8];
#pragma unroll
      for (int mi = 0; mi < 2; ++mi)
        acc[mi][g] = __builtin_amdgcn_mfma_f32_16x16x32_bf16((g < 3) ? ay[mi] : ah[mi], b,
                                                             acc[mi][g], 0, 0, 0);
    }
  }
  int j = j0 + 16 * wv + ml;
  float bi_r = bih[j], bi_z = bih[512 + j], bi_n = bih[1024 + j];
  float bh_r = bhh[j], bh_z = bhh[512 + j], bh_n = bhh[1024 + j];
#pragma unroll
  for (int mi = 0; mi < 2; ++mi)
#pragma unroll
    for (int r = 0; r < 4; ++r) {
      size_t row = (size_t)(m0 + 16 * mi + 4 * qd + r);
      float rg = acc[mi][0][r] + bi_r + acc[mi][3][r] + bh_r;
      rg = 1.f / (1.f + __expf(-rg));
      float zg = acc[mi][1][r] + bi_z + acc[mi][4][r] + bh_z;
      zg = 1.f / (1.f + __expf(-zg));
      float ng = tanhf(acc[mi][2][r] + bi_n + rg * (acc[mi][5][r] + bh_n));
      float hp = hprev[row * 512 + j];
      hnew[row * 512 + j] = (1.f - zg) * ng + zg * hp;
    }
}

__global__ void zero_h(float* hf) {
  int i = blockIdx.x * 256 + threadIdx.x;
  hf[i] = 0.f;
}

// ---------------------------------------------------------------------------
extern "C" void kernel_launch(void* const* d_in, const int* in_sizes, int n_in,
                              void* d_out, int out_size, void* d_ws, size_t ws_size,
                              hipStream_t stream) {
  (void)in_sizes; (void)n_in; (void)out_size; (void)ws_size;
  const float* xs    = (const float*)d_in[0];
  const float* obsW  = (const float*)d_in[1];
  const float* obsb  = (const float*)d_in[2];
  const float* obsg  = (const float*)d_in[3];
  const float* obsbe = (const float*)d_in[4];
  const float* W1    = (const float*)d_in[5];
  const float* b1    = (const float*)d_in[6];
  const float* g1    = (const float*)d_in[7];
  const float* be1   = (const float*)d_in[8];
  const float* W2    = (const float*)d_in[9];
  const float* b2    = (const float*)d_in[10];
  const float* g2    = (const float*)d_in[11];
  const float* be2   = (const float*)d_in[12];
  const float* Wo    = (const float*)d_in[13];
  const float* bo    = (const float*)d_in[14];
  const float* Wih   = (const float*)d_in[15];
  const float* bih   = (const float*)d_in[16];
  const float* Whh   = (const float*)d_in[17];
  const float* bhh   = (const float*)d_in[18];

  char* p = (char*)d_ws;
  auto take = [&](size_t bytes) { char* q = p; p += (bytes + 255) & ~(size_t)255; return q; };
  unsigned short* W1t  = (unsigned short*)take((size_t)512 * 512 * 2);
  unsigned short* W2t  = (unsigned short*)take((size_t)512 * 512 * 2);
  unsigned short* Wot  = (unsigned short*)take((size_t)512 * 512 * 2);
  unsigned short* Wiht = (unsigned short*)take((size_t)1536 * 512 * 2);
  unsigned short* Whht = (unsigned short*)take((size_t)1536 * 512 * 2);
  float* hf0 = (float*)take((size_t)1024 * 512 * 4);
  float* hf1 = (float*)take((size_t)1024 * 512 * 4);
  unsigned short* Yb = (unsigned short*)take((size_t)65536 * 512 * 2);

  dim3 tb(32, 8);
  tile_weight<<<128, 256, 0, stream>>>(W1, W1t);  // first 512 of 513 rows
  tile_weight<<<128, 256, 0, stream>>>(W2, W2t);
  tile_weight<<<128, 256, 0, stream>>>(Wo, Wot);
  transpose_f2b<<<dim3(48, 16), tb, 0, stream>>>(Wih, Wiht, 512, 1536);
  transpose_f2b<<<dim3(48, 16), tb, 0, stream>>>(Whh, Whht, 512, 1536);

  obs_embed<<<16384, 256, 0, stream>>>(xs, obsW, obsb, obsg, obsbe, Yb);

  // tr = W1 row 512 (time row), folded into layer-1 bias per eval.
  ode_mega<<<2048, 512, 0, stream>>>(Yb, W1t, W2t, Wot, b1, W1 + 512 * 512, g1, be1, b2, g2,
                                     be2, bo);

  zero_h<<<2048, 256, 0, stream>>>(hf0);
  float* hf[2] = {hf0, hf1};
  for (int t = 0; t < 64; ++t) {
    int s = t & 1, d = s ^ 1;
    float* hn = (t == 63) ? (float*)d_out : hf[d];
    gru_step<<<dim3(32, 8), 256, 0, stream>>>(Yb + (size_t)t * 1024 * 512, hf[s], hn, Wiht, Whht,
                                              bih, bhh);
  }
}